// Round 10
// baseline (100.119 us; speedup 1.0000x reference)
//
#include <hip/hip_runtime.h>
#include <hip/hip_bf16.h>

#define NB 8
#define NC 16
#define NH 256
#define NW 256
#define ALIVE_THRESH 0.1f
#define UPDATE_RATE 0.25f

typedef __attribute__((ext_vector_type(8))) short bf16x8;
typedef __attribute__((ext_vector_type(4))) float f32x4;
typedef unsigned short ushort_t;

#define MFMA16(a, b, c) __builtin_amdgcn_mfma_f32_16x16x32_bf16((a), (b), (c), 0, 0, 0)

static __device__ __forceinline__ unsigned short f2bf(float f) {
    __hip_bfloat16 h = __float2bfloat16(f);          // RNE
    return __builtin_bit_cast(unsigned short, h);
}
static __device__ __forceinline__ float bf2f(unsigned short b) {
    union { unsigned u; float f; } x; x.u = ((unsigned)b) << 16; return x.f;
}
static __device__ __forceinline__ unsigned pack2(float lo, float hi) {
    return (unsigned)f2bf(lo) | ((unsigned)f2bf(hi) << 16);
}
static __device__ __forceinline__ float bfbits(unsigned w, int hi) {
    return bf2f((unsigned short)(hi ? (w >> 16) : (w & 0xffffu)));
}

// swizzled byte offset into the [512 px][64 bf16] activation LDS buffer
static __device__ __forceinline__ int ybyte(int px, int g) {
    return px * 128 + ((g ^ (px & 7)) << 4);
}

// ---------------------------------------------------------------------------
// Pre-kernel: pack W1(+b1 as k=48 row), W2, W3 into MFMA A-fragment order.
// ---------------------------------------------------------------------------
__global__ void prep_weights(const float* __restrict__ w1, const float* __restrict__ b1,
                             const float* __restrict__ w2, const float* __restrict__ w3,
                             int4* __restrict__ wf)
{
    const int f = blockIdx.x, l = threadIdx.x;
    const int lq = l >> 4, ln = l & 15;
    union { unsigned short us[8]; int4 v; } u;
    if (f < 8) {
        const int mt = f >> 1, ks = f & 1, m = mt * 16 + ln;
        #pragma unroll
        for (int j = 0; j < 8; ++j) {
            const int k = ks * 32 + lq * 8 + j;
            float v = (k < 48) ? w1[m * 48 + k] : ((k == 48) ? b1[m] : 0.0f);
            u.us[j] = f2bf(v);
        }
    } else if (f < 16) {
        const int ff = f - 8, mt = ff >> 1, ks = ff & 1, m = mt * 16 + ln;
        #pragma unroll
        for (int j = 0; j < 8; ++j)
            u.us[j] = f2bf(w2[m * 64 + (ks * 32 + lq * 8 + j)]);
    } else {
        const int ks = f - 16, m = ln;
        #pragma unroll
        for (int j = 0; j < 8; ++j)
            u.us[j] = f2bf(w3[m * 64 + (ks * 32 + lq * 8 + j)]);
    }
    wf[f * 64 + l] = u.v;
}

// ---------------------------------------------------------------------------
// combine (horizontal sobel from this row's sd) + ybuf fill. Both barriers.
// sdrow points at this thread's row segment [16][256]; px_local = t.
// ---------------------------------------------------------------------------
static __device__ __forceinline__ void combine_store(
    char* yb, const unsigned* sdrow, int px_local, int tcol,
    const float* mreg, const float* dreg)
{
    __syncthreads();                                  // B1: sd ready
    const int tm = (tcol - 1) & 255, tp = (tcol + 1) & 255;
    unsigned yp[24];
    {
        unsigned short ys[48];
        #pragma unroll
        for (int c = 0; c < NC; ++c) {
            unsigned L = sdrow[c * NW + tm], R = sdrow[c * NW + tp];
            float sl = bfbits(L, 0), dl = bfbits(L, 1);
            float sr = bfbits(R, 0), dr = bfbits(R, 1);
            ys[3 * c + 0] = f2bf(mreg[c]);
            ys[3 * c + 1] = f2bf(sr - sl);
            ys[3 * c + 2] = f2bf(dl + 2.0f * dreg[c] + dr);
        }
        #pragma unroll
        for (int i = 0; i < 24; ++i)
            yp[i] = (unsigned)ys[2 * i] | ((unsigned)ys[2 * i + 1] << 16);
    }
    __syncthreads();                                  // B2: sd dead, ybuf safe

    #pragma unroll
    for (int g = 0; g < 6; ++g) {
        union { unsigned w[4]; int4 v; } pk;
        pk.w[0] = yp[4 * g]; pk.w[1] = yp[4 * g + 1];
        pk.w[2] = yp[4 * g + 2]; pk.w[3] = yp[4 * g + 3];
        *(int4*)(yb + ybyte(px_local, g)) = pk.v;
    }
    { int4 br; br.x = 0x3F80; br.y = 0; br.z = 0; br.w = 0;
      *(int4*)(yb + ybyte(px_local, 6)) = br; }       // k=48 -> 1.0 (bias)
    { int4 zz; zz.x = zz.y = zz.z = zz.w = 0;
      *(int4*)(yb + ybyte(px_local, 7)) = zz; }
}

// ---------------------------------------------------------------------------
// MLP GEMM body. px0 in LDS px-space (wave wv owns [wv*64, wv*64+64)).
// Lambdas receive px (LDS space): col = px & 255, row-within-block = px >> 8.
// ---------------------------------------------------------------------------
template<typename ResF, typename OutF>
static __device__ __forceinline__ void mlp_gemm(
    char* yb, int lane, int px0,
    const int4* __restrict__ wf, const float* __restrict__ b2,
    const float* __restrict__ umr, ResF getres, OutF putout)
{
    const int lq = lane >> 4, ln = lane & 15;
    const int col0 = px0 & 255;

    float umv[4];
    #pragma unroll
    for (int nt = 0; nt < 4; ++nt)
        umv[nt] = (umr[col0 + nt * 16 + ln] < UPDATE_RATE) ? 1.0f : 0.0f;

    bf16x8 a1f[8];
    #pragma unroll
    for (int f = 0; f < 8; ++f)
        a1f[f] = __builtin_bit_cast(bf16x8, wf[f * 64 + lane]);

    #pragma unroll
    for (int nt = 0; nt < 4; ++nt) {
        const int px = px0 + nt * 16 + ln;
        bf16x8 bb0 = *(const bf16x8*)(yb + ybyte(px, lq));
        bf16x8 bb1 = *(const bf16x8*)(yb + ybyte(px, 4 + lq));
        #pragma unroll
        for (int mt = 0; mt < 4; ++mt) {
            f32x4 z = {0.f, 0.f, 0.f, 0.f};
            z = MFMA16(a1f[2 * mt],     bb0, z);
            z = MFMA16(a1f[2 * mt + 1], bb1, z);
            union { unsigned w[2]; uint2 v; } pk;
            pk.w[0] = pack2(fmaxf(z[0], 0.f), fmaxf(z[1], 0.f));
            pk.w[1] = pack2(fmaxf(z[2], 0.f), fmaxf(z[3], 0.f));
            *(uint2*)(yb + ybyte(px, 2 * mt + (lq >> 1)) + (lq & 1) * 8) = pk.v;
        }
    }

    bf16x8 a2f[8];
    #pragma unroll
    for (int f = 0; f < 8; ++f)
        a2f[f] = __builtin_bit_cast(bf16x8, wf[(8 + f) * 64 + lane]);
    f32x4 b2v[4];
    #pragma unroll
    for (int mt = 0; mt < 4; ++mt)
        b2v[mt] = *(const f32x4*)(b2 + mt * 16 + lq * 4);

    #pragma unroll
    for (int nt = 0; nt < 4; ++nt) {
        const int px = px0 + nt * 16 + ln;
        bf16x8 bb0 = *(const bf16x8*)(yb + ybyte(px, lq));
        bf16x8 bb1 = *(const bf16x8*)(yb + ybyte(px, 4 + lq));
        #pragma unroll
        for (int mt = 0; mt < 4; ++mt) {
            f32x4 z = {0.f, 0.f, 0.f, 0.f};
            z = MFMA16(a2f[2 * mt],     bb0, z);
            z = MFMA16(a2f[2 * mt + 1], bb1, z);
            z = z + b2v[mt];
            union { unsigned w[2]; uint2 v; } pk;
            pk.w[0] = pack2(fmaxf(z[0], 0.f), fmaxf(z[1], 0.f));
            pk.w[1] = pack2(fmaxf(z[2], 0.f), fmaxf(z[3], 0.f));
            *(uint2*)(yb + ybyte(px, 2 * mt + (lq >> 1)) + (lq & 1) * 8) = pk.v;
        }
    }

    bf16x8 a3f0 = __builtin_bit_cast(bf16x8, wf[16 * 64 + lane]);
    bf16x8 a3f1 = __builtin_bit_cast(bf16x8, wf[17 * 64 + lane]);

    #pragma unroll
    for (int nt = 0; nt < 4; ++nt) {
        const int px = px0 + nt * 16 + ln;
        bf16x8 bb0 = *(const bf16x8*)(yb + ybyte(px, lq));
        bf16x8 bb1 = *(const bf16x8*)(yb + ybyte(px, 4 + lq));
        f32x4 z = {0.f, 0.f, 0.f, 0.f};
        z = MFMA16(a3f0, bb0, z);
        z = MFMA16(a3f1, bb1, z);
        f32x4 res = getres(px, lq);
        #pragma unroll
        for (int r = 0; r < 4; ++r)
            putout(px, lq, r, res[r] + z[r] * umv[nt]);
    }
}

// ---------------------------------------------------------------------------
// First step: f32 planar input -> bf16 planar unmasked state + pre mask.
// 512 threads = 2 rows per block; per-thread code identical to r7.
// ---------------------------------------------------------------------------
__global__ __launch_bounds__(512) void nca_first(
    const float* __restrict__ x,
    const float* __restrict__ um,
    const int4*  __restrict__ wf,
    const float* __restrict__ b2,
    ushort_t* __restrict__ xout,
    unsigned char* __restrict__ preb_out)
{
    __shared__ char smem[512 * 128];          // 64 KB; sd overlays first 32 KB
    char*     yb = smem;
    unsigned* sd = (unsigned*)smem;           // [2][16][256]

    const int t = threadIdx.x, bx = blockIdx.x;
    const int h0 = ((((bx & 7) << 4) | (bx >> 3)) << 1);  // XCD-chunked row pair
    const int trow = t >> 8, tcol = t & 255;
    const int h = h0 + trow;
    const int b = blockIdx.y;
    const int hm = (h - 1) & 255, hp = (h + 1) & 255;
    const size_t cs = (size_t)NH * NW;
    const size_t base = (size_t)b * NC * cs;
    const size_t prow = (size_t)b * NH;

    // ---- pre-alive: 3x3 f32 alpha window ------------------------------------
    {
        const float* a3p = x + base + 3 * cs;
        float mx = -1e30f;
        #pragma unroll
        for (int r = 0; r < 3; ++r) {
            const float* rp = a3p + (size_t)((h - 1 + r) & 255) * NW;
            #pragma unroll
            for (int d = 0; d < 3; ++d)
                mx = fmaxf(mx, rp[(tcol - 1 + d) & 255]);
        }
        preb_out[(prow + h) * NW + tcol] = (mx > ALIVE_THRESH) ? 1 : 0;
    }

    // ---- vertical smooth/diff -> sd -----------------------------------------
    unsigned* sdrow = sd + trow * (NC * NW);
    float mreg[NC], dreg[NC];
    #pragma unroll
    for (int c = 0; c < NC; ++c) {
        const float* xc = x + base + (size_t)c * cs;
        float top = xc[(size_t)hm * NW + tcol];
        float mid = xc[(size_t)h  * NW + tcol];
        float bot = xc[(size_t)hp * NW + tcol];
        sdrow[c * NW + tcol] = pack2(top + 2.0f * mid + bot, bot - top);
        mreg[c] = mid; dreg[c] = bot - top;
    }

    combine_store(yb, sdrow, t, tcol, mreg, dreg);

    const int lane = t & 63, wv = t >> 6;
    const int hw = h0 + (wv >> 2);                 // this wave's row
    const float* umr = um + (prow + hw) * NW;

    auto getres = [&](int px, int lq) -> f32x4 {
        f32x4 r;
        #pragma unroll
        for (int i = 0; i < 4; ++i)
            r[i] = x[base + (size_t)(lq * 4 + i) * cs + (size_t)hw * NW + (px & 255)];
        return r;
    };
    auto putout = [&](int px, int lq, int r, float v) {
        xout[base + (size_t)(lq * 4 + r) * cs + (size_t)hw * NW + (px & 255)] = f2bf(v);
    };
    mlp_gemm(yb, lane, wv * 64, wf, b2, umr, getres, putout);
}

// ---------------------------------------------------------------------------
// Later steps: bf16 planar state + prev pre mask in; register 5x5 masks.
// 512 threads = 2 rows per block.
// ---------------------------------------------------------------------------
__global__ __launch_bounds__(512) void nca_step(
    const ushort_t* __restrict__ xin,
    const unsigned char* __restrict__ preb_in,
    const float* __restrict__ um,
    const int4*  __restrict__ wf,
    const float* __restrict__ b2,
    ushort_t* __restrict__ xout,
    unsigned char* __restrict__ preb_out)
{
    __shared__ char smem[512 * 128];          // 64 KB
    char*     yb = smem;
    unsigned* sd = (unsigned*)smem;

    const int t = threadIdx.x, bx = blockIdx.x;
    const int h0 = ((((bx & 7) << 4) | (bx >> 3)) << 1);
    const int trow = t >> 8, tcol = t & 255;
    const int h = h0 + trow;
    const int b = blockIdx.y;
    const int hm = (h - 1) & 255, hp = (h + 1) & 255;
    const size_t cs = (size_t)NH * NW;
    const size_t base = (size_t)b * NC * cs;
    const size_t prow = (size_t)b * NH;

    // ---- 5x5 alpha window (planar, coalesced) -------------------------------
    float a[5][5];
    {
        const ushort_t* a3p = xin + base + 3 * cs;
        #pragma unroll
        for (int j = 0; j < 5; ++j) {
            const ushort_t* rp = a3p + (size_t)((h - 2 + j) & 255) * NW;
            #pragma unroll
            for (int d = 0; d < 5; ++d)
                a[j][d] = bf2f(rp[(tcol - 2 + d) & 255]);
        }
    }

    // ---- post(prev) & combined masks, rows h-1..h+1 x cols tcol-1..tcol+1 ---
    float m3x3[3][3];
    #pragma unroll
    for (int r = 0; r < 3; ++r) {
        float cm[5];
        #pragma unroll
        for (int d = 0; d < 5; ++d)
            cm[d] = fmaxf(fmaxf(a[r][d], a[r + 1][d]), a[r + 2][d]);
        #pragma unroll
        for (int dd = 0; dd < 3; ++dd) {
            float post = fmaxf(fmaxf(cm[dd], cm[dd + 1]), cm[dd + 2]);
            const int hh = (h - 1 + r) & 255, uu = (tcol - 1 + dd) & 255;
            unsigned char p = preb_in[(prow + hh) * NW + uu];
            m3x3[r][dd] = (post > ALIVE_THRESH && p) ? 1.0f : 0.0f;
        }
    }

    // ---- pre mask of THIS step ----------------------------------------------
    {
        float pm = 0.0f;
        #pragma unroll
        for (int r = 0; r < 3; ++r)
            #pragma unroll
            for (int dd = 0; dd < 3; ++dd)
                pm = fmaxf(pm, a[1 + r][1 + dd] * m3x3[r][dd]);
        preb_out[(prow + h) * NW + tcol] = (pm > ALIVE_THRESH) ? 1 : 0;
    }

    const float m0 = m3x3[0][1], m1 = m3x3[1][1], m2 = m3x3[2][1];

    // ---- vertical smooth/diff on masked state -> sd (planar loads) ----------
    unsigned* sdrow = sd + trow * (NC * NW);
    float mreg[NC], dreg[NC];
    #pragma unroll
    for (int c = 0; c < NC; ++c) {
        float top, mid, bot;
        if (c == 3) { top = a[1][2] * m0; mid = a[2][2] * m1; bot = a[3][2] * m2; }
        else {
            const ushort_t* xc = xin + base + (size_t)c * cs;
            top = bf2f(xc[(size_t)hm * NW + tcol]) * m0;
            mid = bf2f(xc[(size_t)h  * NW + tcol]) * m1;
            bot = bf2f(xc[(size_t)hp * NW + tcol]) * m2;
        }
        sdrow[c * NW + tcol] = pack2(top + 2.0f * mid + bot, bot - top);
        mreg[c] = mid; dreg[c] = bot - top;
    }

    combine_store(yb, sdrow, t, tcol, mreg, dreg);

    const int lane = t & 63, wv = t >> 6;
    const int hw = h0 + (wv >> 2);
    const float* umr = um + (prow + hw) * NW;

    // residual mask via wave shuffle (owner lane = px & 63, same wave/row)
    auto getres = [&](int px, int lq) -> f32x4 {
        const float mm = __shfl(m1, px & 63);
        f32x4 r;
        #pragma unroll
        for (int i = 0; i < 4; ++i)
            r[i] = bf2f(xin[base + (size_t)(lq * 4 + i) * cs + (size_t)hw * NW + (px & 255)]) * mm;
        return r;
    };
    auto putout = [&](int px, int lq, int r, float v) {
        xout[base + (size_t)(lq * 4 + r) * cs + (size_t)hw * NW + (px & 255)] = f2bf(v);
    };
    mlp_gemm(yb, lane, wv * 64, wf, b2, umr, getres, putout);
}

// ---------------------------------------------------------------------------
// Final: post-alive on bf16 planar state, apply pre*post, f32 planar out.
// At its BW roofline (~49 MB); unchanged from r7.
// ---------------------------------------------------------------------------
__global__ __launch_bounds__(256) void nca_final(
    const ushort_t* __restrict__ xin,
    const unsigned char* __restrict__ preb,
    float* __restrict__ xout)
{
    const int t = threadIdx.x, bx = blockIdx.x;
    const int h = ((bx & 7) << 5) | (bx >> 3);
    const int b = blockIdx.y;
    const size_t cs = (size_t)NH * NW;
    const size_t base = (size_t)b * NC * cs;

    const ushort_t* a3p = xin + base + 3 * cs;
    float mx = -1e30f;
    #pragma unroll
    for (int r = 0; r < 3; ++r) {
        const ushort_t* rp = a3p + (size_t)((h - 1 + r) & 255) * NW;
        #pragma unroll
        for (int d = 0; d < 3; ++d)
            mx = fmaxf(mx, bf2f(rp[(t - 1 + d) & 255]));
    }
    const float m = (mx > ALIVE_THRESH && preb[((size_t)b * NH + h) * NW + t])
                        ? 1.0f : 0.0f;

    const size_t off = (size_t)h * NW + t;
    #pragma unroll
    for (int c = 0; c < NC; ++c)
        xout[base + (size_t)c * cs + off] = bf2f(xin[base + (size_t)c * cs + off]) * m;
}

// ---------------------------------------------------------------------------
extern "C" void kernel_launch(void* const* d_in, const int* in_sizes, int n_in,
                              void* d_out, int out_size, void* d_ws, size_t ws_size,
                              hipStream_t stream) {
    const float* x  = (const float*)d_in[0];
    const float* w1 = (const float*)d_in[1];
    const float* b1 = (const float*)d_in[2];
    const float* w2 = (const float*)d_in[3];
    const float* b2 = (const float*)d_in[4];
    const float* w3 = (const float*)d_in[5];
    const float* um = (const float*)d_in[6];
    const int steps = in_sizes[6] / (NB * NH * NW);

    const size_t npix  = (size_t)NB * NH * NW;
    const size_t nelem = (size_t)NB * NC * NH * NW;

    ushort_t* bfA        = (ushort_t*)d_ws;                 // 16 MB
    ushort_t* bfB        = bfA + nelem;                     // 16 MB
    unsigned char* prebA = (unsigned char*)(bfB + nelem);   // 512 KB
    unsigned char* prebB = prebA + npix;                    // 512 KB
    int4* wf             = (int4*)(prebB + npix);           // 18 KB
    float* xout          = (float*)d_out;

    prep_weights<<<18, 64, 0, stream>>>(w1, b1, w2, w3, wf);

    dim3 grd2(NH / 2, NB);    // 2 rows per block
    dim3 grd1(NH, NB);

    const ushort_t* cur = bfA;
    unsigned char* preb_last = prebA;

    for (int i = 0; i < steps; ++i) {
        const float* um_i = um + (size_t)i * npix;
        ushort_t* bfo      = (i % 2 == 0) ? bfA : bfB;
        unsigned char* po  = (i % 2 == 0) ? prebA : prebB;
        unsigned char* pin = (i % 2 == 0) ? prebB : prebA;

        if (i == 0)
            nca_first<<<grd2, 512, 0, stream>>>(x, um_i, wf, b2, bfo, po);
        else
            nca_step<<<grd2, 512, 0, stream>>>(cur, pin, um_i, wf, b2, bfo, po);
        cur = bfo;
        preb_last = po;
    }

    nca_final<<<grd1, 256, 0, stream>>>(cur, preb_last, xout);
}

// Round 11
// 63.418 us; speedup vs baseline: 1.5787x; 1.5787x over previous
//
#include <hip/hip_runtime.h>
#include <hip/hip_bf16.h>

#define NB 8
#define NC 16
#define NH 256
#define NW 256
#define ALIVE_THRESH 0.1f
#define UPDATE_RATE 0.25f

typedef __attribute__((ext_vector_type(8))) short bf16x8;
typedef __attribute__((ext_vector_type(4))) float f32x4;
typedef unsigned short ushort_t;

#define MFMA16(a, b, c) __builtin_amdgcn_mfma_f32_16x16x32_bf16((a), (b), (c), 0, 0, 0)

static __device__ __forceinline__ unsigned short f2bf(float f) {
    __hip_bfloat16 h = __float2bfloat16(f);          // RNE
    return __builtin_bit_cast(unsigned short, h);
}
static __device__ __forceinline__ float bf2f(unsigned short b) {
    union { unsigned u; float f; } x; x.u = ((unsigned)b) << 16; return x.f;
}
static __device__ __forceinline__ unsigned pack2(float lo, float hi) {
    return (unsigned)f2bf(lo) | ((unsigned)f2bf(hi) << 16);
}
static __device__ __forceinline__ float bfbits(unsigned w, int hi) {
    return bf2f((unsigned short)(hi ? (w >> 16) : (w & 0xffffu)));
}

// swizzled byte offset into the [256 px][64 bf16] activation LDS buffer
static __device__ __forceinline__ int ybyte(int px, int g) {
    return px * 128 + ((g ^ (px & 7)) << 4);
}

// hoisted weight fragments + b2 (T14 issue-early: loaded at kernel entry,
// before the mask/sd phase; constant indices only -> stays in registers).
struct WFrags {
    bf16x8 a1[8];
    bf16x8 a2[8];
    bf16x8 a3[2];
    f32x4  b2v[4];
};

static __device__ __forceinline__ WFrags load_wfrags(
    const int4* __restrict__ wf, const float* __restrict__ b2, int lane)
{
    WFrags w;
    #pragma unroll
    for (int f = 0; f < 8; ++f)
        w.a1[f] = __builtin_bit_cast(bf16x8, wf[f * 64 + lane]);
    #pragma unroll
    for (int f = 0; f < 8; ++f)
        w.a2[f] = __builtin_bit_cast(bf16x8, wf[(8 + f) * 64 + lane]);
    w.a3[0] = __builtin_bit_cast(bf16x8, wf[16 * 64 + lane]);
    w.a3[1] = __builtin_bit_cast(bf16x8, wf[17 * 64 + lane]);
    const int lq = lane >> 4;
    #pragma unroll
    for (int mt = 0; mt < 4; ++mt)
        w.b2v[mt] = *(const f32x4*)(b2 + mt * 16 + lq * 4);
    return w;
}

// ---------------------------------------------------------------------------
// Pre-kernel: pack W1(+b1 as k=48 row), W2, W3 into MFMA A-fragment order.
// ---------------------------------------------------------------------------
__global__ void prep_weights(const float* __restrict__ w1, const float* __restrict__ b1,
                             const float* __restrict__ w2, const float* __restrict__ w3,
                             int4* __restrict__ wf)
{
    const int f = blockIdx.x, l = threadIdx.x;
    const int lq = l >> 4, ln = l & 15;
    union { unsigned short us[8]; int4 v; } u;
    if (f < 8) {
        const int mt = f >> 1, ks = f & 1, m = mt * 16 + ln;
        #pragma unroll
        for (int j = 0; j < 8; ++j) {
            const int k = ks * 32 + lq * 8 + j;
            float v = (k < 48) ? w1[m * 48 + k] : ((k == 48) ? b1[m] : 0.0f);
            u.us[j] = f2bf(v);
        }
    } else if (f < 16) {
        const int ff = f - 8, mt = ff >> 1, ks = ff & 1, m = mt * 16 + ln;
        #pragma unroll
        for (int j = 0; j < 8; ++j)
            u.us[j] = f2bf(w2[m * 64 + (ks * 32 + lq * 8 + j)]);
    } else {
        const int ks = f - 16, m = ln;
        #pragma unroll
        for (int j = 0; j < 8; ++j)
            u.us[j] = f2bf(w3[m * 64 + (ks * 32 + lq * 8 + j)]);
    }
    wf[f * 64 + l] = u.v;
}

// ---------------------------------------------------------------------------
// combine (horizontal sobel from sd LDS) + ybuf fill. Contains both barriers.
// ---------------------------------------------------------------------------
static __device__ __forceinline__ void combine_store(
    char* yb, unsigned* sd, int t, const float* mreg, const float* dreg)
{
    __syncthreads();                                  // B1: sd ready
    const int tm = (t - 1) & 255, tp = (t + 1) & 255;
    unsigned yp[24];
    {
        unsigned short ys[48];
        #pragma unroll
        for (int c = 0; c < NC; ++c) {
            unsigned L = sd[c * NW + tm], R = sd[c * NW + tp];
            float sl = bfbits(L, 0), dl = bfbits(L, 1);
            float sr = bfbits(R, 0), dr = bfbits(R, 1);
            ys[3 * c + 0] = f2bf(mreg[c]);
            ys[3 * c + 1] = f2bf(sr - sl);
            ys[3 * c + 2] = f2bf(dl + 2.0f * dreg[c] + dr);
        }
        #pragma unroll
        for (int i = 0; i < 24; ++i)
            yp[i] = (unsigned)ys[2 * i] | ((unsigned)ys[2 * i + 1] << 16);
    }
    __syncthreads();                                  // B2: sd dead, ybuf safe

    #pragma unroll
    for (int g = 0; g < 6; ++g) {
        union { unsigned w[4]; int4 v; } pk;
        pk.w[0] = yp[4 * g]; pk.w[1] = yp[4 * g + 1];
        pk.w[2] = yp[4 * g + 2]; pk.w[3] = yp[4 * g + 3];
        *(int4*)(yb + ybyte(t, g)) = pk.v;
    }
    { int4 br; br.x = 0x3F80; br.y = 0; br.z = 0; br.w = 0;
      *(int4*)(yb + ybyte(t, 6)) = br; }              // k=48 -> 1.0 (bias)
    { int4 zz; zz.x = zz.y = zz.z = zz.w = 0;
      *(int4*)(yb + ybyte(t, 7)) = zz; }
}

// ---------------------------------------------------------------------------
// MLP GEMM body. Weights already in registers (wfr). um via own-lane shuffle.
// ---------------------------------------------------------------------------
template<typename ResF, typename OutF>
static __device__ __forceinline__ void mlp_gemm(
    char* yb, int lane, int px0, const WFrags& wfr, float um_own,
    ResF getres, OutF putout)
{
    const int lq = lane >> 4, ln = lane & 15;

    float umv[4];
    #pragma unroll
    for (int nt = 0; nt < 4; ++nt)
        umv[nt] = (__shfl(um_own, nt * 16 + ln) < UPDATE_RATE) ? 1.0f : 0.0f;

    #pragma unroll
    for (int nt = 0; nt < 4; ++nt) {
        const int px = px0 + nt * 16 + ln;
        bf16x8 bb0 = *(const bf16x8*)(yb + ybyte(px, lq));
        bf16x8 bb1 = *(const bf16x8*)(yb + ybyte(px, 4 + lq));
        #pragma unroll
        for (int mt = 0; mt < 4; ++mt) {
            f32x4 z = {0.f, 0.f, 0.f, 0.f};
            z = MFMA16(wfr.a1[2 * mt],     bb0, z);
            z = MFMA16(wfr.a1[2 * mt + 1], bb1, z);
            union { unsigned w[2]; uint2 v; } pk;
            pk.w[0] = pack2(fmaxf(z[0], 0.f), fmaxf(z[1], 0.f));
            pk.w[1] = pack2(fmaxf(z[2], 0.f), fmaxf(z[3], 0.f));
            *(uint2*)(yb + ybyte(px, 2 * mt + (lq >> 1)) + (lq & 1) * 8) = pk.v;
        }
    }

    #pragma unroll
    for (int nt = 0; nt < 4; ++nt) {
        const int px = px0 + nt * 16 + ln;
        bf16x8 bb0 = *(const bf16x8*)(yb + ybyte(px, lq));
        bf16x8 bb1 = *(const bf16x8*)(yb + ybyte(px, 4 + lq));
        #pragma unroll
        for (int mt = 0; mt < 4; ++mt) {
            f32x4 z = {0.f, 0.f, 0.f, 0.f};
            z = MFMA16(wfr.a2[2 * mt],     bb0, z);
            z = MFMA16(wfr.a2[2 * mt + 1], bb1, z);
            z = z + wfr.b2v[mt];
            union { unsigned w[2]; uint2 v; } pk;
            pk.w[0] = pack2(fmaxf(z[0], 0.f), fmaxf(z[1], 0.f));
            pk.w[1] = pack2(fmaxf(z[2], 0.f), fmaxf(z[3], 0.f));
            *(uint2*)(yb + ybyte(px, 2 * mt + (lq >> 1)) + (lq & 1) * 8) = pk.v;
        }
    }

    #pragma unroll
    for (int nt = 0; nt < 4; ++nt) {
        const int px = px0 + nt * 16 + ln;
        bf16x8 bb0 = *(const bf16x8*)(yb + ybyte(px, lq));
        bf16x8 bb1 = *(const bf16x8*)(yb + ybyte(px, 4 + lq));
        f32x4 z = {0.f, 0.f, 0.f, 0.f};
        z = MFMA16(wfr.a3[0], bb0, z);
        z = MFMA16(wfr.a3[1], bb1, z);
        f32x4 res = getres(px, lq);
        #pragma unroll
        for (int r = 0; r < 4; ++r)
            putout(px, lq, r, res[r] + z[r] * umv[nt]);
    }
}

// ---------------------------------------------------------------------------
// First step: f32 planar input -> bf16 planar unmasked state + pre mask.
// ---------------------------------------------------------------------------
__global__ __launch_bounds__(256, 3) void nca_first(
    const float* __restrict__ x,
    const float* __restrict__ um,
    const int4*  __restrict__ wf,
    const float* __restrict__ b2,
    ushort_t* __restrict__ xout,
    unsigned char* __restrict__ preb_out)
{
    __shared__ char smem[256 * 128];          // 32 KB; sd overlays ybuf
    char*     yb = smem;
    unsigned* sd = (unsigned*)smem;

    const int t = threadIdx.x, bx = blockIdx.x;
    const int h = ((bx & 7) << 5) | (bx >> 3);       // XCD-chunked row swizzle
    const int b = blockIdx.y;
    const int hm = (h - 1) & 255, hp = (h + 1) & 255;
    const size_t cs = (size_t)NH * NW;
    const size_t base = (size_t)b * NC * cs;
    const size_t prow = (size_t)b * NH;
    const int lane = t & 63;

    // ---- issue-early loads: weights + um (independent of everything) -------
    const WFrags wfr = load_wfrags(wf, b2, lane);
    const float um_own = um[(prow + h) * NW + t];

    // ---- pre-alive: 3x3 f32 alpha window ------------------------------------
    {
        const float* a3p = x + base + 3 * cs;
        float mx = -1e30f;
        #pragma unroll
        for (int r = 0; r < 3; ++r) {
            const float* rp = a3p + (size_t)((h - 1 + r) & 255) * NW;
            #pragma unroll
            for (int d = 0; d < 3; ++d)
                mx = fmaxf(mx, rp[(t - 1 + d) & 255]);
        }
        preb_out[(prow + h) * NW + t] = (mx > ALIVE_THRESH) ? 1 : 0;
    }

    // ---- vertical smooth/diff -> sd -----------------------------------------
    float mreg[NC], dreg[NC];
    #pragma unroll
    for (int c = 0; c < NC; ++c) {
        const float* xc = x + base + (size_t)c * cs;
        float top = xc[(size_t)hm * NW + t];
        float mid = xc[(size_t)h  * NW + t];
        float bot = xc[(size_t)hp * NW + t];
        sd[c * NW + t] = pack2(top + 2.0f * mid + bot, bot - top);
        mreg[c] = mid; dreg[c] = bot - top;
    }

    combine_store(yb, sd, t, mreg, dreg);

    const int wv = t >> 6;

    auto getres = [&](int px, int lq) -> f32x4 {
        f32x4 r;
        #pragma unroll
        for (int i = 0; i < 4; ++i)
            r[i] = x[base + (size_t)(lq * 4 + i) * cs + (size_t)h * NW + px];
        return r;
    };
    auto putout = [&](int px, int lq, int r, float v) {
        xout[base + (size_t)(lq * 4 + r) * cs + (size_t)h * NW + px] = f2bf(v);
    };
    mlp_gemm(yb, lane, wv * 64, wfr, um_own, getres, putout);
}

// ---------------------------------------------------------------------------
// Later steps: bf16 planar state + prev pre mask in; register 5x5 masks.
// ---------------------------------------------------------------------------
__global__ __launch_bounds__(256, 3) void nca_step(
    const ushort_t* __restrict__ xin,
    const unsigned char* __restrict__ preb_in,
    const float* __restrict__ um,
    const int4*  __restrict__ wf,
    const float* __restrict__ b2,
    ushort_t* __restrict__ xout,
    unsigned char* __restrict__ preb_out)
{
    __shared__ char smem[256 * 128];
    char*     yb = smem;
    unsigned* sd = (unsigned*)smem;

    const int t = threadIdx.x, bx = blockIdx.x;
    const int h = ((bx & 7) << 5) | (bx >> 3);
    const int b = blockIdx.y;
    const int hm = (h - 1) & 255, hp = (h + 1) & 255;
    const size_t cs = (size_t)NH * NW;
    const size_t base = (size_t)b * NC * cs;
    const size_t prow = (size_t)b * NH;
    const int lane = t & 63;

    // ---- issue-early loads: weights + um ------------------------------------
    const WFrags wfr = load_wfrags(wf, b2, lane);
    const float um_own = um[(prow + h) * NW + t];

    // ---- 5x5 alpha window (planar, coalesced) -------------------------------
    float a[5][5];
    {
        const ushort_t* a3p = xin + base + 3 * cs;
        #pragma unroll
        for (int j = 0; j < 5; ++j) {
            const ushort_t* rp = a3p + (size_t)((h - 2 + j) & 255) * NW;
            #pragma unroll
            for (int d = 0; d < 5; ++d)
                a[j][d] = bf2f(rp[(t - 2 + d) & 255]);
        }
    }

    // ---- post(prev) & combined masks, rows h-1..h+1 x cols t-1..t+1 ---------
    float m3x3[3][3];
    #pragma unroll
    for (int r = 0; r < 3; ++r) {
        float cm[5];
        #pragma unroll
        for (int d = 0; d < 5; ++d)
            cm[d] = fmaxf(fmaxf(a[r][d], a[r + 1][d]), a[r + 2][d]);
        #pragma unroll
        for (int dd = 0; dd < 3; ++dd) {
            float post = fmaxf(fmaxf(cm[dd], cm[dd + 1]), cm[dd + 2]);
            const int hh = (h - 1 + r) & 255, uu = (t - 1 + dd) & 255;
            unsigned char p = preb_in[(prow + hh) * NW + uu];
            m3x3[r][dd] = (post > ALIVE_THRESH && p) ? 1.0f : 0.0f;
        }
    }

    // ---- pre mask of THIS step ----------------------------------------------
    {
        float pm = 0.0f;
        #pragma unroll
        for (int r = 0; r < 3; ++r)
            #pragma unroll
            for (int dd = 0; dd < 3; ++dd)
                pm = fmaxf(pm, a[1 + r][1 + dd] * m3x3[r][dd]);
        preb_out[(prow + h) * NW + t] = (pm > ALIVE_THRESH) ? 1 : 0;
    }

    const float m0 = m3x3[0][1], m1 = m3x3[1][1], m2 = m3x3[2][1];

    // ---- vertical smooth/diff on masked state -> sd (planar loads) ----------
    float mreg[NC], dreg[NC];
    #pragma unroll
    for (int c = 0; c < NC; ++c) {
        float top, mid, bot;
        if (c == 3) { top = a[1][2] * m0; mid = a[2][2] * m1; bot = a[3][2] * m2; }
        else {
            const ushort_t* xc = xin + base + (size_t)c * cs;
            top = bf2f(xc[(size_t)hm * NW + t]) * m0;
            mid = bf2f(xc[(size_t)h  * NW + t]) * m1;
            bot = bf2f(xc[(size_t)hp * NW + t]) * m2;
        }
        sd[c * NW + t] = pack2(top + 2.0f * mid + bot, bot - top);
        mreg[c] = mid; dreg[c] = bot - top;
    }

    combine_store(yb, sd, t, mreg, dreg);

    const int wv = t >> 6;

    // residual mask for px via wave shuffle (wave wv owns px = wv*64 + lane)
    auto getres = [&](int px, int lq) -> f32x4 {
        const float mm = __shfl(m1, px & 63);
        f32x4 r;
        #pragma unroll
        for (int i = 0; i < 4; ++i)
            r[i] = bf2f(xin[base + (size_t)(lq * 4 + i) * cs + (size_t)h * NW + px]) * mm;
        return r;
    };
    auto putout = [&](int px, int lq, int r, float v) {
        xout[base + (size_t)(lq * 4 + r) * cs + (size_t)h * NW + px] = f2bf(v);
    };
    mlp_gemm(yb, lane, wv * 64, wfr, um_own, getres, putout);
}

// ---------------------------------------------------------------------------
// Final: post-alive on bf16 planar state, apply pre*post, f32 planar out.
// Vectorized: 4 px/thread (uint2 loads, float4 stores). BW-bound.
// ---------------------------------------------------------------------------
__global__ __launch_bounds__(256) void nca_final(
    const ushort_t* __restrict__ xin,
    const unsigned char* __restrict__ preb,
    float* __restrict__ xout)
{
    const int t = threadIdx.x, bx = blockIdx.x;
    const int b = blockIdx.y;
    const int h = (bx << 2) | (t >> 6);              // 4 rows per block
    const int px0 = (t & 63) << 2;                   // 4 px per thread
    const size_t cs = (size_t)NH * NW;
    const size_t base = (size_t)b * NC * cs;
    const size_t prow = (size_t)b * NH;

    const ushort_t* a3p = xin + base + 3 * cs;
    float m0 = -1e30f, m1 = -1e30f, m2 = -1e30f, m3 = -1e30f;
    #pragma unroll
    for (int r = 0; r < 3; ++r) {
        const ushort_t* rp = a3p + (size_t)((h - 1 + r) & 255) * NW;
        uint2 mid = *(const uint2*)(rp + px0);
        float v0 = bfbits(mid.x, 0), v1 = bfbits(mid.x, 1);
        float v2 = bfbits(mid.y, 0), v3 = bfbits(mid.y, 1);
        float lm = bf2f(rp[(px0 - 1) & 255]);
        float rm = bf2f(rp[(px0 + 4) & 255]);
        m0 = fmaxf(m0, fmaxf(fmaxf(lm, v0), v1));
        m1 = fmaxf(m1, fmaxf(fmaxf(v0, v1), v2));
        m2 = fmaxf(m2, fmaxf(fmaxf(v1, v2), v3));
        m3 = fmaxf(m3, fmaxf(fmaxf(v2, v3), rm));
    }
    const size_t pix = (prow + h) * NW + px0;
    const unsigned pr4 = *(const unsigned*)(preb + pix);   // 4 bytes, aligned
    const float f0 = (m0 > ALIVE_THRESH && (pr4 & 0x000000FFu)) ? 1.0f : 0.0f;
    const float f1 = (m1 > ALIVE_THRESH && (pr4 & 0x0000FF00u)) ? 1.0f : 0.0f;
    const float f2 = (m2 > ALIVE_THRESH && (pr4 & 0x00FF0000u)) ? 1.0f : 0.0f;
    const float f3 = (m3 > ALIVE_THRESH && (pr4 & 0xFF000000u)) ? 1.0f : 0.0f;

    #pragma unroll
    for (int c = 0; c < NC; ++c) {
        const size_t o = base + (size_t)c * cs + (size_t)h * NW + px0;
        uint2 s = *(const uint2*)(xin + o);
        float4 v;
        v.x = bfbits(s.x, 0) * f0;
        v.y = bfbits(s.x, 1) * f1;
        v.z = bfbits(s.y, 0) * f2;
        v.w = bfbits(s.y, 1) * f3;
        *(float4*)(xout + o) = v;
    }
}

// ---------------------------------------------------------------------------
extern "C" void kernel_launch(void* const* d_in, const int* in_sizes, int n_in,
                              void* d_out, int out_size, void* d_ws, size_t ws_size,
                              hipStream_t stream) {
    const float* x  = (const float*)d_in[0];
    const float* w1 = (const float*)d_in[1];
    const float* b1 = (const float*)d_in[2];
    const float* w2 = (const float*)d_in[3];
    const float* b2 = (const float*)d_in[4];
    const float* w3 = (const float*)d_in[5];
    const float* um = (const float*)d_in[6];
    const int steps = in_sizes[6] / (NB * NH * NW);

    const size_t npix  = (size_t)NB * NH * NW;
    const size_t nelem = (size_t)NB * NC * NH * NW;

    ushort_t* bfA        = (ushort_t*)d_ws;                 // 16 MB
    ushort_t* bfB        = bfA + nelem;                     // 16 MB
    unsigned char* prebA = (unsigned char*)(bfB + nelem);   // 512 KB
    unsigned char* prebB = prebA + npix;                    // 512 KB
    int4* wf             = (int4*)(prebB + npix);           // 18 KB
    float* xout          = (float*)d_out;

    prep_weights<<<18, 64, 0, stream>>>(w1, b1, w2, w3, wf);

    dim3 grd(NH, NB);
    dim3 grdF(NH / 4, NB);

    const ushort_t* cur = bfA;
    unsigned char* preb_last = prebA;

    for (int i = 0; i < steps; ++i) {
        const float* um_i = um + (size_t)i * npix;
        ushort_t* bfo      = (i % 2 == 0) ? bfA : bfB;
        unsigned char* po  = (i % 2 == 0) ? prebA : prebB;
        unsigned char* pin = (i % 2 == 0) ? prebB : prebA;

        if (i == 0)
            nca_first<<<grd, 256, 0, stream>>>(x, um_i, wf, b2, bfo, po);
        else
            nca_step<<<grd, 256, 0, stream>>>(cur, pin, um_i, wf, b2, bfo, po);
        cur = bfo;
        preb_last = po;
    }

    nca_final<<<grdF, 256, 0, stream>>>(cur, preb_last, xout);
}